// Round 2
// baseline (164.448 us; speedup 1.0000x reference)
//
#include <hip/hip_runtime.h>

// PeriodicEmbedding: out[b, n*64+o] = relu( sum_i emb[b,n,i] * W[n,i,o] + bias[n,o] )
//   emb[b,n,i] = sin(2*pi*coef[n,i]*x[b,n])     i in [0,32)
//              = cos(2*pi*coef[n,i-32]*x[b,n])  i in [32,64)
// B=8192, N=256, D=64. Output f32 512 MB -> HBM-write-bound.
//
// R1 changes vs R0 (108.8 us):
//  - Swapped MFMA operands (D = W_frag x emb_frag): output D row = o, so each
//    lane holds 4 consecutive o values -> float4 stores (32 scalar -> 8 x dwordx4).
//  - W pre-converted f32->bf16 ONCE into d_ws (fragment-ordered, 8 KB/token),
//    removing per-block staging + barrier + LDS from the main kernel.

typedef short bf16x8 __attribute__((ext_vector_type(8)));
typedef float f32x4 __attribute__((ext_vector_type(4)));

#define BM 128   // rows per block (4 waves x 32 rows)

__device__ __forceinline__ short f2bf(float f) {
    unsigned u = __float_as_uint(f);
    unsigned r = (u + 0x7FFFu + ((u >> 16) & 1u)) >> 16;   // RNE
    return (short)r;
}

// ---------------- kernel 1: W [N][64][64] f32 -> fragment-ordered bf16 ----------------
// ws layout per token n (4096 bf16 = 8 KB): chunk c in [0,512), 8 bf16 each:
//   c = (((nf*2 + ki)*4 + lg)*16 + lr);  element j in [0,8)
//   value = W[n][k][o] with o = nf*16+lr, k = ki*32 + lg*8 + j
// so in the main kernel, fragment (nf,ki) for lane l is the contiguous 16 B at
//   wt + n*4096 + ((nf*2+ki)*64 + l)*8     (one 1 KB coalesced burst per wave)
__global__ __launch_bounds__(256) void pe_wconv(
    const float* __restrict__ wgt, short* __restrict__ wt)
{
    __shared__ float lw[64 * 65];            // [k][o], stride 65 to kill bank conflicts
    const int n = blockIdx.x;
    const int t = threadIdx.x;

    const float4* Wn4 = (const float4*)(wgt + n * 4096);
    #pragma unroll
    for (int it = 0; it < 4; ++it) {
        int idx4 = it * 256 + t;             // coalesced float4 read
        float4 v = Wn4[idx4];
        int flat = idx4 * 4;
        int k = flat >> 6, o = flat & 63;    // W[n][k][o]
        lw[k * 65 + o + 0] = v.x;
        lw[k * 65 + o + 1] = v.y;
        lw[k * 65 + o + 2] = v.z;
        lw[k * 65 + o + 3] = v.w;
    }
    __syncthreads();

    short* outp = wt + n * 4096;
    #pragma unroll
    for (int half = 0; half < 2; ++half) {
        int c  = half * 256 + t;
        int lr = c & 15, lg = (c >> 4) & 3, ki = (c >> 6) & 1, nf = c >> 7;
        int o  = nf * 16 + lr;
        int kb = ki * 32 + lg * 8;
        bf16x8 pk;
        #pragma unroll
        for (int j = 0; j < 8; ++j) pk[j] = f2bf(lw[(kb + j) * 65 + o]);
        *(bf16x8*)(outp + c * 8) = pk;       // coalesced dwordx4 write
    }
}

// ---------------- kernel 2: main (ws path, no LDS, no barrier) ----------------
__global__ __launch_bounds__(256) void pe_main_ws(
    const float* __restrict__ x,     // [B, N]
    const float* __restrict__ coef,  // [N, 32]
    const short* __restrict__ wt,    // [N][512][8] bf16 fragment-ordered
    const float* __restrict__ bias,  // [N, 64]
    float* __restrict__ out)         // [B, 16384]
{
    const int N = 256;
    const int bid = blockIdx.x;
    const int n   = bid & (N - 1);          // token fastest -> x-line L2 reuse
    const int b0  = (bid >> 8) * BM;

    const int t  = threadIdx.x;
    const int w  = t >> 6;
    const int l  = t & 63;
    const int lr = l & 15;
    const int lg = l >> 4;

    // W fragments: A-operand, row(o)=lr, k=lg*8+j  -- contiguous 16 B per lane
    const short* wtn = wt + n * 4096;
    bf16x8 bfr[4][2];
    #pragma unroll
    for (int nf = 0; nf < 4; ++nf)
        #pragma unroll
        for (int ki = 0; ki < 2; ++ki)
            bfr[nf][ki] = *(const bf16x8*)(wtn + ((nf * 2 + ki) * 64 + l) * 8);

    // coef slice for this lane's k slots
    const float* cp = coef + n * 32 + lg * 8;
    float c[8];
    #pragma unroll
    for (int j = 0; j < 8; ++j) c[j] = cp[j];

    // x for the two 16-row fragments this wave covers
    const int row0 = b0 + w * 32 + lr;
    const float x0 = x[row0 * N + n];
    const float x1 = x[(row0 + 16) * N + n];

    // emb fragments in registers: B-operand, col(brow)=lr, k=lg*8+j
    bf16x8 a_s[2], a_c[2];
    #pragma unroll
    for (int m = 0; m < 2; ++m) {
        float xv = m ? x1 : x0;
        #pragma unroll
        for (int j = 0; j < 8; ++j) {
            float tt = c[j] * xv;
            tt = __builtin_amdgcn_fractf(tt);        // sin(2*pi*t) = v_sin(fract(t))
            a_s[m][j] = f2bf(__builtin_amdgcn_sinf(tt));
            a_c[m][j] = f2bf(__builtin_amdgcn_cosf(tt));
        }
    }

    // D = W_frag x emb_frag: D row = o (lane gets 4 consecutive o), D col = brow
    f32x4 acc[2][4];
    #pragma unroll
    for (int m = 0; m < 2; ++m)
        #pragma unroll
        for (int nf = 0; nf < 4; ++nf) {
            f32x4 z = {0.f, 0.f, 0.f, 0.f};
            z = __builtin_amdgcn_mfma_f32_16x16x32_bf16(bfr[nf][0], a_s[m], z, 0, 0, 0);
            z = __builtin_amdgcn_mfma_f32_16x16x32_bf16(bfr[nf][1], a_c[m], z, 0, 0, 0);
            acc[m][nf] = z;
        }

    // epilogue: +bias, relu, float4 stores (o = nf*16 + lg*4 + r contiguous)
    const float* bn = bias + n * 64;
    f32x4 bv[4];
    #pragma unroll
    for (int nf = 0; nf < 4; ++nf)
        bv[nf] = *(const f32x4*)(bn + nf * 16 + lg * 4);

    #pragma unroll
    for (int m = 0; m < 2; ++m) {
        int row = b0 + w * 32 + m * 16 + lr;
        float* op = out + (size_t)row * 16384 + n * 64 + lg * 4;
        #pragma unroll
        for (int nf = 0; nf < 4; ++nf) {
            f32x4 v = acc[m][nf] + bv[nf];
            f32x4 r;
            #pragma unroll
            for (int q = 0; q < 4; ++q) r[q] = fmaxf(v[q], 0.0f);
            *(f32x4*)(op + nf * 16) = r;
        }
    }
}

// ---------------- fallback: in-kernel LDS staging (if ws too small) ----------------
#define LDW 72
__global__ __launch_bounds__(256) void pe_mfma_fallback(
    const float* __restrict__ x, const float* __restrict__ coef,
    const float* __restrict__ wgt, const float* __restrict__ bias,
    float* __restrict__ out)
{
    const int N = 256;
    const int bid = blockIdx.x;
    const int n   = bid & (N - 1);
    const int b0  = (bid >> 8) * BM;

    __shared__ short wtl[64 * LDW];
    const int t = threadIdx.x;

    const float* Wn = wgt + n * 4096;
    #pragma unroll
    for (int it = 0; it < 16; ++it) {
        int idx = it * 256 + t;
        int i = idx >> 6, o = idx & 63;
        wtl[o * LDW + i] = f2bf(Wn[idx]);
    }
    __syncthreads();

    const int w = t >> 6, l = t & 63, lr = l & 15, lg = l >> 4;

    const float* cp = coef + n * 32 + lg * 8;
    float c[8];
    #pragma unroll
    for (int j = 0; j < 8; ++j) c[j] = cp[j];

    const int row0 = b0 + w * 32 + lr;
    const float x0 = x[row0 * N + n];
    const float x1 = x[(row0 + 16) * N + n];

    bf16x8 a_s[2], a_c[2];
    #pragma unroll
    for (int m = 0; m < 2; ++m) {
        float xv = m ? x1 : x0;
        #pragma unroll
        for (int j = 0; j < 8; ++j) {
            float tt = c[j] * xv;
            tt = __builtin_amdgcn_fractf(tt);
            a_s[m][j] = f2bf(__builtin_amdgcn_sinf(tt));
            a_c[m][j] = f2bf(__builtin_amdgcn_cosf(tt));
        }
    }

    bf16x8 bfr[4][2];
    #pragma unroll
    for (int nf = 0; nf < 4; ++nf) {
        int col = nf * 16 + lr;
        #pragma unroll
        for (int ki = 0; ki < 2; ++ki)
            bfr[nf][ki] = *(const bf16x8*)(&wtl[col * LDW + ki * 32 + lg * 8]);
    }

    f32x4 acc[2][4];
    #pragma unroll
    for (int m = 0; m < 2; ++m)
        #pragma unroll
        for (int nf = 0; nf < 4; ++nf) {
            f32x4 z = {0.f, 0.f, 0.f, 0.f};
            z = __builtin_amdgcn_mfma_f32_16x16x32_bf16(bfr[nf][0], a_s[m], z, 0, 0, 0);
            z = __builtin_amdgcn_mfma_f32_16x16x32_bf16(bfr[nf][1], a_c[m], z, 0, 0, 0);
            acc[m][nf] = z;
        }

    const float* bn = bias + n * 64;
    f32x4 bv[4];
    #pragma unroll
    for (int nf = 0; nf < 4; ++nf)
        bv[nf] = *(const f32x4*)(bn + nf * 16 + lg * 4);

    #pragma unroll
    for (int m = 0; m < 2; ++m) {
        int row = b0 + w * 32 + m * 16 + lr;
        float* op = out + (size_t)row * 16384 + n * 64 + lg * 4;
        #pragma unroll
        for (int nf = 0; nf < 4; ++nf) {
            f32x4 v = acc[m][nf] + bv[nf];
            f32x4 r;
            #pragma unroll
            for (int q = 0; q < 4; ++q) r[q] = fmaxf(v[q], 0.0f);
            *(f32x4*)(op + nf * 16) = r;
        }
    }
}

extern "C" void kernel_launch(void* const* d_in, const int* in_sizes, int n_in,
                              void* d_out, int out_size, void* d_ws, size_t ws_size,
                              hipStream_t stream) {
    const float* x    = (const float*)d_in[0];
    const float* coef = (const float*)d_in[1];
    const float* wgt  = (const float*)d_in[2];
    const float* bias = (const float*)d_in[3];
    float* out = (float*)d_out;

    const size_t wt_bytes = 256 * 4096 * sizeof(short);  // 2 MB
    if (ws_size >= wt_bytes) {
        short* wt = (short*)d_ws;
        hipLaunchKernelGGL(pe_wconv, dim3(256), dim3(256), 0, stream, wgt, wt);
        hipLaunchKernelGGL(pe_main_ws, dim3(256 * (8192 / BM)), dim3(256), 0, stream,
                           x, coef, (const short*)wt, bias, out);
    } else {
        hipLaunchKernelGGL(pe_mfma_fallback, dim3(256 * (8192 / BM)), dim3(256), 0, stream,
                           x, coef, wgt, bias, out);
    }
}

// Round 3
// 108.357 us; speedup vs baseline: 1.5177x; 1.5177x over previous
//
#include <hip/hip_runtime.h>

// PeriodicEmbedding: out[b, n*64+o] = relu( sum_i emb[b,n,i] * W[n,i,o] + bias[n,o] )
//   emb[b,n,i] = sin(2*pi*coef[n,i]*x[b,n])     i in [0,32)
//              = cos(2*pi*coef[n,i-32]*x[b,n])  i in [32,64)
// B=8192, N=256, D=64. Output f32 512 MB -> HBM-write-bound (~83 us floor).
//
// History: R0 (LDS-staged, scalar stores) = 108.8 us. R1 (ws-preconverted W,
// 2 kernels) = 164.4 us REGRESSION -> cold per-block global fragment loads on
// the critical path; reverted to LDS staging.
// R2: single kernel, stage W[n] once per block, process TILES=4 row-tiles of
// 128 rows with it (staging traffic /4, barriers /4). Swapped MFMA operands
// (D = W x emb) so each lane holds 4 consecutive o -> float4 stores.

typedef short bf16x8 __attribute__((ext_vector_type(8)));
typedef float f32x4 __attribute__((ext_vector_type(4)));

#define BM    128   // rows per tile (4 waves x 32 rows)
#define TILES 4     // tiles per block -> 512 rows per block
#define LDW   72    // LDS row stride (bf16) for Wt: 144 B, keeps b128 16B-aligned

__device__ __forceinline__ short f2bf(float f) {
    unsigned u = __float_as_uint(f);
    unsigned r = (u + 0x7FFFu + ((u >> 16) & 1u)) >> 16;   // RNE
    return (short)r;
}

__global__ __launch_bounds__(256) void pe_kernel(
    const float* __restrict__ x,     // [B, N]
    const float* __restrict__ coef,  // [N, 32]
    const float* __restrict__ wgt,   // [N, 64, 64]  (i=k, o)
    const float* __restrict__ bias,  // [N, 64]
    float* __restrict__ out)         // [B, 16384]
{
    const int N = 256;
    const int bid = blockIdx.x;
    const int n      = bid & (N - 1);                 // token fastest -> x-line L2 reuse
    const int b_base = (bid >> 8) * (BM * TILES);

    __shared__ short wtl[64 * LDW];                   // Wt[o][k] bf16
    const int t = threadIdx.x;

    // ---- stage W[n] transposed into LDS as bf16 (once per block) ----
    const float* Wn = wgt + n * 4096;
    #pragma unroll
    for (int it = 0; it < 16; ++it) {
        int idx = it * 256 + t;                       // coalesced f32 read
        int i = idx >> 6, o = idx & 63;               // W[n][i][o]
        wtl[o * LDW + i] = f2bf(Wn[idx]);
    }
    __syncthreads();

    const int w  = t >> 6;
    const int l  = t & 63;
    const int lr = l & 15;
    const int lg = l >> 4;

    // ---- W fragments (A operand: row = o = nf*16+lr, k = ki*32+lg*8+j), once ----
    bf16x8 bfr[4][2];
    #pragma unroll
    for (int nf = 0; nf < 4; ++nf)
        #pragma unroll
        for (int ki = 0; ki < 2; ++ki)
            bfr[nf][ki] = *(const bf16x8*)(&wtl[(nf * 16 + lr) * LDW + ki * 32 + lg * 8]);

    // ---- coef slice for this lane's k slots, once ----
    const float* cp = coef + n * 32 + lg * 8;
    float c[8];
    #pragma unroll
    for (int j = 0; j < 8; ++j) c[j] = cp[j];

    // ---- bias (o = nf*16 + lg*4 + q), once ----
    const float* bn = bias + n * 64;
    f32x4 bv[4];
    #pragma unroll
    for (int nf = 0; nf < 4; ++nf)
        bv[nf] = *(const f32x4*)(bn + nf * 16 + lg * 4);

    // ---- per-tile: x load -> sincos -> MFMA -> store ----
    for (int tt = 0; tt < TILES; ++tt) {
        const int b0   = b_base + tt * BM;
        const int row0 = b0 + w * 32 + lr;
        const float x0 = x[row0 * N + n];
        const float x1 = x[(row0 + 16) * N + n];

        // emb fragments (B operand: col = row-of-out-block = lr, k = lg*8+j)
        bf16x8 a_s[2], a_c[2];
        #pragma unroll
        for (int m = 0; m < 2; ++m) {
            float xv = m ? x1 : x0;
            #pragma unroll
            for (int j = 0; j < 8; ++j) {
                float v = c[j] * xv;
                v = __builtin_amdgcn_fractf(v);            // sin(2*pi*t)=v_sin(fract(t))
                a_s[m][j] = f2bf(__builtin_amdgcn_sinf(v));
                a_c[m][j] = f2bf(__builtin_amdgcn_cosf(v));
            }
        }

        // D = W x emb: D row = o (4 consecutive per lane), D col = b-row
        f32x4 acc[2][4];
        #pragma unroll
        for (int m = 0; m < 2; ++m)
            #pragma unroll
            for (int nf = 0; nf < 4; ++nf) {
                f32x4 z = {0.f, 0.f, 0.f, 0.f};
                z = __builtin_amdgcn_mfma_f32_16x16x32_bf16(bfr[nf][0], a_s[m], z, 0, 0, 0);
                z = __builtin_amdgcn_mfma_f32_16x16x32_bf16(bfr[nf][1], a_c[m], z, 0, 0, 0);
                acc[m][nf] = z;
            }

        // epilogue: +bias, relu, float4 stores (o = nf*16 + lg*4 + q contiguous)
        #pragma unroll
        for (int m = 0; m < 2; ++m) {
            int row = b0 + w * 32 + m * 16 + lr;
            float* op = out + (size_t)row * 16384 + n * 64 + lg * 4;
            #pragma unroll
            for (int nf = 0; nf < 4; ++nf) {
                f32x4 v = acc[m][nf] + bv[nf];
                f32x4 r;
                #pragma unroll
                for (int q = 0; q < 4; ++q) r[q] = fmaxf(v[q], 0.0f);
                *(f32x4*)(op + nf * 16) = r;
            }
        }
    }
}

extern "C" void kernel_launch(void* const* d_in, const int* in_sizes, int n_in,
                              void* d_out, int out_size, void* d_ws, size_t ws_size,
                              hipStream_t stream) {
    const float* x    = (const float*)d_in[0];
    const float* coef = (const float*)d_in[1];
    const float* wgt  = (const float*)d_in[2];
    const float* bias = (const float*)d_in[3];
    float* out = (float*)d_out;

    dim3 grid(256 * (8192 / (BM * TILES)));   // 4096 blocks, token index fastest
    dim3 block(256);
    hipLaunchKernelGGL(pe_kernel, grid, block, 0, stream,
                       x, coef, wgt, bias, out);
}